// Round 1
// baseline (39.018 us; speedup 1.0000x reference)
//
#include <hip/hip_runtime.h>
#include <math.h>

#define TWO_PI 6.2831853071795864769f

// ws layout (floats):
//   [0,     8192)  phi: 16 states x 256 amps x {re,im}
//   [8192, 10240)  H:   8 q x 16 x 16
//   [10240,42976)  y1:  32 x 1023
//   [42976,44000)  partials: 1024
// total 176,000 bytes

__device__ __forceinline__ float2 cmul(float2 a, float2 b) {
    return make_float2(fmaf(a.x, b.x, -a.y * b.y), fmaf(a.x, b.y, a.y * b.x));
}
__device__ __forceinline__ float2 cadd(float2 a, float2 b) {
    return make_float2(a.x + b.x, a.y + b.y);
}

// Apply a 2x2 gate on bit position `pos` (pos = 7 - qubit). 64-thread block,
// each lane handles 2 of the 128 pairs. One barrier per gate.
__device__ void gate1(float2* psi, int pos, float2 U00, float2 U01, float2 U10, float2 U11) {
    int lane = threadIdx.x;
    int b = 1 << pos, low = b - 1;
#pragma unroll
    for (int t = 0; t < 2; ++t) {
        int p = lane + 64 * t;
        int k0 = ((p & ~low) << 1) | (p & low);
        int k1 = k0 | b;
        float2 v0 = psi[k0], v1 = psi[k1];
        float2 n0 = cadd(cmul(U00, v0), cmul(U01, v1));
        float2 n1 = cadd(cmul(U10, v0), cmul(U11, v1));
        psi[k0] = n0; psi[k1] = n1;
    }
    __syncthreads();
}

__device__ void cnotg(float2* psi, int posc, int post) {
    int lane = threadIdx.x;
    int b = 1 << post, low = b - 1, cb = 1 << posc;
#pragma unroll
    for (int t = 0; t < 2; ++t) {
        int p = lane + 64 * t;
        int k0 = ((p & ~low) << 1) | (p & low);
        int k1 = k0 | b;
        if (k0 & cb) { float2 v0 = psi[k0], v1 = psi[k1]; psi[k0] = v1; psi[k1] = v0; }
    }
    __syncthreads();
}

// custom_ansatz: per wire j -> RX(w[j]); CNOT; RY(w[j]); CNOT; RZ(w[j])
__device__ void ansatz(float2* psi, const float* wl) {
    for (int j = 0; j < 8; ++j) {
        int c = (j < 7) ? j : 0;
        int tq = (j < 7) ? j + 1 : 7;
        float sh, ch;
        sincosf(0.5f * wl[j], &sh, &ch);
        int pos = 7 - j;
        gate1(psi, pos, make_float2(ch, 0.f), make_float2(0.f, -sh),
                        make_float2(0.f, -sh), make_float2(ch, 0.f));      // RX
        cnotg(psi, 7 - c, 7 - tq);
        gate1(psi, pos, make_float2(ch, 0.f), make_float2(-sh, 0.f),
                        make_float2(sh, 0.f), make_float2(ch, 0.f));       // RY
        cnotg(psi, 7 - c, 7 - tq);
        gate1(psi, pos, make_float2(ch, -sh), make_float2(0.f, 0.f),
                        make_float2(0.f, 0.f), make_float2(ch, sh));       // RZ
    }
}

// K1: phi_S = ansatz(w2) ansatz(w1) B_S ansatz(w0) |0>, one block per S.
__global__ __launch_bounds__(64) void k_phi(const float* wt, float2* phi) {
    __shared__ float2 psi[256];
    __shared__ float wl[24];
    int lane = threadIdx.x;
    if (lane < 24) {
        float th = wt[lane];
        th = th - floorf(th / TWO_PI) * TWO_PI;   // jnp.mod(w, 2pi)
        wl[lane] = th;
    }
#pragma unroll
    for (int r = 0; r < 4; ++r) {
        int k = lane * 4 + r;
        psi[k] = make_float2(k == 0 ? 1.f : 0.f, 0.f);
    }
    __syncthreads();
    ansatz(psi, wl);
    // B_S = tensor of Y' = [[0,-1],[1,0]] on qubits in S (qubit q -> bit 7-q)
    int S = blockIdx.x;
    int sbits = ((S & 1) << 7) | ((S & 2) << 5) | ((S & 4) << 3) | ((S & 8) << 1);
    float2 tmp[4]; float sg[4];
#pragma unroll
    for (int r = 0; r < 4; ++r) {
        int k = lane * 4 + r;
        tmp[r] = psi[k ^ sbits];
        sg[r] = (__popc(sbits & ~k) & 1) ? -1.f : 1.f;
    }
    __syncthreads();
#pragma unroll
    for (int r = 0; r < 4; ++r) {
        int k = lane * 4 + r;
        psi[k] = make_float2(sg[r] * tmp[r].x, sg[r] * tmp[r].y);
    }
    __syncthreads();
    ansatz(psi, wl + 8);
    ansatz(psi, wl + 16);
#pragma unroll
    for (int r = 0; r < 4; ++r) {
        int k = lane * 4 + r;
        phi[S * 256 + k] = psi[k];
    }
}

// K2: H_q[i][j] = sum_k z_q(k) Re(conj(phi_i[k]) phi_j[k]), one block per (i,j).
__global__ __launch_bounds__(64) void k_h(const float2* phi, float* H) {
    int i = blockIdx.x >> 4, j = blockIdx.x & 15;
    int lane = threadIdx.x;
    float acc[8] = {0.f, 0.f, 0.f, 0.f, 0.f, 0.f, 0.f, 0.f};
#pragma unroll
    for (int r = 0; r < 4; ++r) {
        int k = lane * 4 + r;
        float2 a = phi[i * 256 + k], b = phi[j * 256 + k];
        float p = a.x * b.x + a.y * b.y;
#pragma unroll
        for (int q = 0; q < 8; ++q)
            acc[q] += ((k >> (7 - q)) & 1) ? -p : p;
    }
#pragma unroll
    for (int q = 0; q < 8; ++q) {
#pragma unroll
        for (int off = 32; off >= 1; off >>= 1)
            acc[q] += __shfl_xor(acc[q], off);
    }
    if (lane == 0) {
#pragma unroll
        for (int q = 0; q < 8; ++q)
            H[q * 256 + i * 16 + j] = acc[q];
    }
}

// monomial vector: m[s] = prod_q (s>>q&1 ? sin(a_q/2) : cos(a_q/2))
__device__ __forceinline__ void build_m(const float* cc, const float* ss, float* m) {
    float m01[4] = {cc[0] * cc[1], ss[0] * cc[1], cc[0] * ss[1], ss[0] * ss[1]};
    float m23[4] = {cc[2] * cc[3], ss[2] * cc[3], cc[2] * ss[3], ss[2] * ss[3]};
#pragma unroll
    for (int u = 0; u < 16; ++u) m[u] = m01[u & 3] * m23[u >> 2];
}

// K3: layer-1, only <Z_0> needed. y1[b][s] = relu(m^T H0 m)
__global__ __launch_bounds__(256) void k_l1(const float* x, const float* H, float* y1) {
    __shared__ float H0[256];
    H0[threadIdx.x] = H[threadIdx.x];
    __syncthreads();
    int t = blockIdx.x * 256 + threadIdx.x;
    if (t >= 32 * 1023) return;
    int b = t / 1023;
    int s = t - b * 1023;
    float cc[4], ss[4];
#pragma unroll
    for (int i = 0; i < 4; ++i) {
        int l = s + i - 1;                      // PAD=1
        float a = (l >= 0 && l < 1024) ? x[b * 1024 + l] : 0.f;
        sincosf(0.5f * a, &ss[i], &cc[i]);
    }
    float m[16];
    build_m(cc, ss, m);
    float y = 0.f;
#pragma unroll
    for (int i2 = 0; i2 < 16; ++i2) {
        float ti = 0.f;
#pragma unroll
        for (int j2 = 0; j2 < 16; ++j2) ti = fmaf(H0[i2 * 16 + j2], m[j2], ti);
        y = fmaf(m[i2], ti, y);
    }
    y1[b * 1023 + s] = fmaxf(y, 0.f);
}

// K4: layer-2 + channel max-pool + dense dot partials.
// 8 threads per window (one per q). 32 blocks per batch, 32 windows per block.
#define HSTRIDE 260   // 260 % 32 == 4 -> q*260 spreads 8 q over 8 banks; 16B aligned
__global__ __launch_bounds__(256) void k_l2(const float* y1, const float* dw,
                                            const float* H, float* partials) {
    __shared__ float Hs[8 * HSTRIDE];
#pragma unroll
    for (int u = 0; u < 8; ++u) Hs[u * HSTRIDE + threadIdx.x] = H[u * 256 + threadIdx.x];
    __syncthreads();
    int blk = blockIdx.x;
    int b = blk >> 5;
    int c = blk & 31;
    int widx = c * 32 + (threadIdx.x >> 3);     // window in [0,1024), valid < 1022
    int q = threadIdx.x & 7;
    float yq = -1e30f;
    if (widx < 1022) {
        float cc[4], ss[4];
#pragma unroll
        for (int i = 0; i < 4; ++i) {
            int l = widx + i - 1;
            float a = (l >= 0 && l < 1023) ? y1[b * 1023 + l] : 0.f;
            sincosf(0.5f * a, &ss[i], &cc[i]);
        }
        float m[16];
        build_m(cc, ss, m);
        const float* Hq = &Hs[q * HSTRIDE];
        float y = 0.f;
#pragma unroll
        for (int i2 = 0; i2 < 16; ++i2) {
            float ti = 0.f;
#pragma unroll
            for (int j2 = 0; j2 < 16; ++j2) ti = fmaf(Hq[i2 * 16 + j2], m[j2], ti);
            y = fmaf(m[i2], ti, y);
        }
        yq = y;
    }
    // max over the 8 q-lanes of this window group
    yq = fmaxf(yq, __shfl_xor(yq, 1));
    yq = fmaxf(yq, __shfl_xor(yq, 2));
    yq = fmaxf(yq, __shfl_xor(yq, 4));
    float contrib = 0.f;
    if (q == 0 && widx < 1022) contrib = fmaxf(yq, 0.f) * dw[widx];
    __shared__ float red[256];
    red[threadIdx.x] = contrib;
    __syncthreads();
    for (int off = 128; off >= 1; off >>= 1) {
        if (threadIdx.x < off) red[threadIdx.x] += red[threadIdx.x + off];
        __syncthreads();
    }
    if (threadIdx.x == 0) partials[blk] = red[0];
}

// K5: out[b] = sum of 32 partials + bias. Fully rewrites d_out every call.
__global__ __launch_bounds__(64) void k_out(const float* partials, const float* db, float* out) {
    int b = threadIdx.x;
    if (b < 32) {
        float s = db[0];
        for (int c = 0; c < 32; ++c) s += partials[b * 32 + c];
        out[b] = s;
    }
}

extern "C" void kernel_launch(void* const* d_in, const int* in_sizes, int n_in,
                              void* d_out, int out_size, void* d_ws, size_t ws_size,
                              hipStream_t stream) {
    const float* x  = (const float*)d_in[0];   // (32,1024,1)
    const float* wt = (const float*)d_in[1];   // (3,8)
    const float* dw = (const float*)d_in[2];   // (1022,1)
    const float* db = (const float*)d_in[3];   // (1,)
    float* wsf = (float*)d_ws;
    float2* phi     = (float2*)wsf;            // 8192 floats
    float* H        = wsf + 8192;              // 2048 floats
    float* y1       = wsf + 10240;             // 32736 floats
    float* partials = wsf + 42976;             // 1024 floats
    float* out = (float*)d_out;

    hipLaunchKernelGGL(k_phi, dim3(16),   dim3(64),  0, stream, wt, phi);
    hipLaunchKernelGGL(k_h,   dim3(256),  dim3(64),  0, stream, (const float2*)phi, H);
    hipLaunchKernelGGL(k_l1,  dim3(128),  dim3(256), 0, stream, x, H, y1);
    hipLaunchKernelGGL(k_l2,  dim3(1024), dim3(256), 0, stream, y1, dw, H, partials);
    hipLaunchKernelGGL(k_out, dim3(1),    dim3(64),  0, stream, partials, db, out);
}